// Round 1
// 260.886 us; speedup vs baseline: 1.2479x; 1.2479x over previous
//
#include <hip/hip_runtime.h>

using u16 = unsigned short;
using u32 = unsigned int;
using u64 = unsigned long long;

typedef _Float16 half8 __attribute__((ext_vector_type(8)));
typedef float  f32x4 __attribute__((ext_vector_type(4)));
typedef u32    u32x4 __attribute__((ext_vector_type(4)));
typedef u32    u32x2 __attribute__((ext_vector_type(2)));

#define T_STEPS 24
#define NB 4096
#define NF 1024
#define NH 256
#define NCLS 10

// split f32 -> hi + 2^-12*lo (lo stored pre-scaled); per-term err ~2^-23|w|
static __device__ __forceinline__ void f16split(float w, u16& hi, u16& lo) {
  _Float16 h = (_Float16)w;
  float hf = (float)h;
  if (__builtin_fabsf(hf) < 6.103515625e-05f) { h = (_Float16)0.0f; hf = 0.0f; }
  float r = __fmul_rn(__fsub_rn(w, hf), 4096.0f);   // exact residual * 2^12
  _Float16 l = (_Float16)r;
  hi = __builtin_bit_cast(u16, h);
  lo = __builtin_bit_cast(u16, l);
}

// ---------------------------------------------------------------------------
// Prep: W1/W2/W3 -> f16 planes INTERLEAVED per 64-k block: row n holds
// [hi(k 0..63) | lo(k 0..63) | hi(k 64..127) | lo(...)...] so consecutive
// 64-k super-chunks in the GEMM are hi/lo of the SAME spike bits.
// B'[cls][t*256+h] = alpha_t*Wo[cls][h] (f64 alpha), 2-plane f16 (hi|lo
// halves), padded to 16 cls rows.
// ---------------------------------------------------------------------------
__global__ __launch_bounds__(256) void k_prep(const float* __restrict__ W1,
                                              const float* __restrict__ W2,
                                              const float* __restrict__ W3,
                                              const float* __restrict__ Wo,
                                              u16* __restrict__ W1hl,
                                              u16* __restrict__ W2hl,
                                              u16* __restrict__ W3hl,
                                              u16* __restrict__ Bp) {
  int blk = blockIdx.x, tid = threadIdx.x;
  if (blk < 1536) {
    const float* src; u16* dst; int K; int g;
    if (blk < 1024)      { src = W1; dst = W1hl; K = 1024; g = blk * 256 + tid; }
    else if (blk < 1280) { src = W2; dst = W2hl; K = 256;  g = (blk - 1024) * 256 + tid; }
    else                 { src = W3; dst = W3hl; K = 256;  g = (blk - 1280) * 256 + tid; }
    int n = g / K, k = g - n * K;
    u16 hi, lo;
    f16split(src[g], hi, lo);
    int p = k >> 6, j = k & 63;
    u16* d = dst + (size_t)n * 2 * K + p * 128 + j;
    d[0] = hi;
    d[64] = lo;
  } else {
    int g2 = (blk - 1536) * 256 + tid;      // 0..98303 = 16 cls x 6144
    int cls = g2 / 6144;
    int r = g2 - cls * 6144;
    int t = r >> 8, h = r & 255;
    float val = 0.0f;
    if (cls < NCLS) {
      double s = 0.0, p8 = 1.0;
      for (int m = t + 1; m < 24; ++m) {
        double p9 = 1.0;
        for (int qq = 0; qq < 23 - m; ++qq) p9 *= 0.9;
        s += p9 * p8;
        p8 *= 0.8;
      }
      double alpha = 0.1 * s;
      val = (float)(alpha * (double)Wo[cls * 256 + h]);
    }
    u16 hi, lo;
    f16split(val, hi, lo);
    Bp[(size_t)cls * 12288 + t * 256 + h] = hi;
    Bp[(size_t)cls * 12288 + 6144 + t * 256 + h] = lo;
  }
}

// ---------------------------------------------------------------------------
// One Linear+LIF phase. 8 waves as 2m x 4n (wave tile 48m x 64n, acc[3][4]).
// NSC = K'/64 super-chunks; consecutive (even,odd) SCs are hi/lo planes of
// the SAME k-range: even SC loads A bits + expands 6 f16 fragments (av=1.0);
// odd SC derives lo fragments in-register via packed mul by 2^-12 (exact).
// global_load_lds width-16 XOR-swizzled dbuf staging; fused register LIF.
// ---------------------------------------------------------------------------
template <int NSC, int ASTRIDE>
__device__ __forceinline__ void mega_phase(u16* __restrict__ Bs,
                                           const u32* __restrict__ alds,
                                           const u16* __restrict__ wsrc,
                                           u32* __restrict__ zdst,
                                           float scale,
                                           int wid, int lane, int wm, int wn) {
  constexpr int KTOT = NSC * 64;   // u16 per weight row

  const int bsh   = (lane >> 4) * 8;
  const int rbase = (wn * 64 + (lane & 15)) * 64;   // u16 (128 B LDS rows)
  int pu8[2];
  #pragma unroll
  for (int h = 0; h < 2; ++h)
    pu8[h] = (((4 * h + (lane >> 4)) ^ (lane & 7)) * 8);
  const int sunit = ((lane & 7) ^ (lane >> 3)) * 8;  // u16, XOR swizzle
  const u16* gs = wsrc + (size_t)(wid * 32 + (lane >> 3)) * KTOT + sunit;
  const int ldsw = wid * 2048;                       // u16: 32 rows x 64

  auto stage = [&](int s, int b) {
    const u16* g = gs + s * 64;
    #pragma unroll
    for (int r = 0; r < 4; ++r)
      __builtin_amdgcn_global_load_lds(
          (const __attribute__((address_space(1))) u32*)(g + (size_t)r * 8 * KTOT),
          (__attribute__((address_space(3))) u32*)&Bs[b * 16384 + ldsw + r * 512],
          16, 0, 0);
  };

  int arow[3];
  #pragma unroll
  for (int ms = 0; ms < 3; ++ms)
    arow[ms] = (wm * 48 + ms * 16 + (lane & 15)) * ASTRIDE;

  auto expand = [&](u32 word) -> half8 {
    u32 by = (word >> bsh) & 0xFFu;
    u32 sp = by * 0x8001u;
    u32x4 d;
    d.x = (sp & 0x10001u) * 0x3C00u;
    d.y = ((sp >> 2) & 0x10001u) * 0x3C00u;
    d.z = ((sp >> 4) & 0x10001u) * 0x3C00u;
    d.w = ((sp >> 6) & 0x10001u) * 0x3C00u;
    return __builtin_bit_cast(half8, d);
  };

  const _Float16 scl = (_Float16)2.44140625e-4f;   // 2^-12, exact in f16
  const half8 sc8 = {scl, scl, scl, scl, scl, scl, scl, scl};

  f32x4 acc[3][4];
  #pragma unroll
  for (int ms = 0; ms < 3; ++ms)
    #pragma unroll
    for (int ns = 0; ns < 4; ++ns)
      #pragma unroll
      for (int i = 0; i < 4; ++i) acc[ms][ns][i] = 0.0f;

  stage(0, 0);

  half8 afr[3][2];
  #pragma unroll 2
  for (int s = 0; s < NSC; ++s) {
    __syncthreads();   // buf[s&1] staged; all waves done with other buf
    if ((s & 1) == 0) {
      // hi SC: fresh bits (words s, s+1 of the row) -> expand at av=1.0
      u32x2 bw[3];
      #pragma unroll
      for (int ms = 0; ms < 3; ++ms)
        bw[ms] = *(const u32x2*)(alds + arow[ms] + s);
      if (s + 1 < NSC) stage(s + 1, (s + 1) & 1);
      #pragma unroll
      for (int ms = 0; ms < 3; ++ms) {
        afr[ms][0] = expand(bw[ms].x);
        afr[ms][1] = expand(bw[ms].y);
      }
    } else {
      // lo SC: same bits, amplitude 2^-12 -- packed mul, exact
      if (s + 1 < NSC) stage(s + 1, (s + 1) & 1);
      #pragma unroll
      for (int ms = 0; ms < 3; ++ms) {
        afr[ms][0] = afr[ms][0] * sc8;
        afr[ms][1] = afr[ms][1] * sc8;
      }
    }

    const int bufo = (s & 1) * 16384;
    #pragma unroll
    for (int h = 0; h < 2; ++h) {
      #pragma unroll
      for (int ns = 0; ns < 4; ++ns) {
        half8 bfr = *(const half8*)&Bs[bufo + rbase + ns * 1024 + pu8[h]];
        #pragma unroll
        for (int ms = 0; ms < 3; ++ms)
          acc[ms][ns] = __builtin_amdgcn_mfma_f32_16x16x32_f16(afr[ms][h], bfr,
                                                               acc[ms][ns], 0, 0, 0);
      }
    }
  }
  __syncthreads();   // staging dead -> reg overlay safe

  // ---- fused LIF: 2 rounds of 32 cols; C/D: col=lane&15, row=q*4+i ----
  float* reg = (float*)Bs + wid * 1600;   // 48 x 33-pad f32 per wave (51.2 KB)
  const int q   = lane >> 4, c16 = lane & 15;
  const int b2  = lane >> 5, c   = lane & 31;

  #pragma unroll
  for (int r = 0; r < 2; ++r) {
    #pragma unroll
    for (int ms = 0; ms < 3; ++ms)
      #pragma unroll
      for (int j = 0; j < 2; ++j)
        #pragma unroll
        for (int i = 0; i < 4; ++i)
          reg[(ms * 16 + q * 4 + i) * 33 + j * 16 + c16] =
              __fmul_rn(scale, acc[ms][2 * r + j][i]);
    // per-wave region: in-wave lgkm ordering suffices (no barrier)
    float v = 0.0f, ii = 0.0f;
    u32 zw = 0;
    #pragma unroll
    for (int t = 0; t < T_STEPS; ++t) {
      float cv = reg[(b2 * 24 + t) * 33 + c];
      float vdec = __fadd_rn(v, __fmul_rn(0.1f, __fsub_rn(ii, v)));
      float idec = __fmul_rn(0.8f, ii);
      bool z = vdec > 0.33f;
      v = z ? 0.0f : vdec;
      ii = __fadd_rn(idec, cv);
      zw |= ((u32)z) << t;
    }
    #pragma unroll
    for (int t = 0; t < T_STEPS; ++t) {
      u64 m = __ballot((zw >> t) & 1u);
      if (c == 0)
        zdst[((wm * 2 + b2) * 24 + t) * 8 + wn * 2 + r] = (u32)(m >> (b2 * 32));
    }
  }
  __syncthreads();   // zdst complete; reg reads done before next stage(0)
}

// ---------------------------------------------------------------------------
// MEGAKERNEL: one block = 4 batches (96 rows, (b,t) order): encoder + all
// three Linear+LIF layers + fused LI readout. Spike bits never leave LDS.
// ---------------------------------------------------------------------------
__global__ __launch_bounds__(512, 4) void k_mega(const float* __restrict__ x,
                                                 const float* __restrict__ fsp,
                                                 const float* __restrict__ esp,
                                                 const u16* __restrict__ W1hl,
                                                 const u16* __restrict__ W2hl,
                                                 const u16* __restrict__ W3hl,
                                                 const u16* __restrict__ Bp,
                                                 float* __restrict__ out) {
  __shared__ __align__(16) u16 Bs[2 * 16384];   // 64 KB staging (+ reg/red overlay)
  __shared__ u32 zE[96 * 34];                   // 13.1 KB enc bits (stride 34; zB overlay)
  __shared__ u32 zA[96 * 8];                    // 3 KB z1 bits (z3 overlay)

  const int tid  = threadIdx.x;
  const int wid  = tid >> 6;
  const int lane = tid & 63;
  const int wm   = wid & 1;
  const int wn   = wid >> 1;          // 0..3
  const int b0   = blockIdx.x * 4;

  // ---- encoder: wave covers (bb = wid>>1, f in [fbase, fbase+512)) ----
  {
    const int bb = wid >> 1;
    const int fbase = (wid & 1) * 512;
    const float c2 = __fmul_rn(2.0f, fsp[0]);
    float cur[8], v[8];
    #pragma unroll
    for (int j = 0; j < 8; ++j) {
      cur[j] = __fmul_rn(c2, x[(size_t)(b0 + bb) * 1024 + fbase + j * 64 + lane]);
      v[j] = 0.0f;
    }
    #pragma unroll
    for (int t = 0; t < T_STEPS; ++t) {
      #pragma unroll
      for (int j = 0; j < 8; ++j) {
        v[j] = __fadd_rn(v[j], __fmul_rn(0.1f, __fsub_rn(cur[j], v[j])));
        bool s = v[j] > 1.0f;
        if (s) v[j] = 0.0f;
        u64 m = __ballot(s);
        if (lane == 0) {
          int w0 = (bb * 24 + t) * 34 + (fbase >> 5) + 2 * j;
          zE[w0] = (u32)m;
          zE[w0 + 1] = (u32)(m >> 32);
        }
      }
    }
  }
  __syncthreads();

  const float s1 = __fmul_rn(1.2f, __fmul_rn(5.0f, esp[0]));
  mega_phase<32, 34>(Bs, zE, W1hl, zA, s1, wid, lane, wm, wn);
  mega_phase<8, 8>(Bs, zA, W2hl, zE, 1.2f, wid, lane, wm, wn);   // zB = zE region
  mega_phase<8, 8>(Bs, zE, W3hl, zA, 1.2f, wid, lane, wm, wn);   // z3 -> zA region

  // ---- fused readout: out[b0+b][cls] = sum_{t,h} z3[b,t,h]*Bp[cls][t*256+h]
  // Wave w handles t in {3w, 3w+1, 3w+2}: 24 words x 2 planes = 48 MFMAs.
  // A-row = batch (rows 0..3 valid), B-col = cls. C rows 0..3 live in q==0.
  {
    const int n = lane & 15;           // batch row (A) and cls col (B)
    const int q = lane >> 4;
    const int bsh2 = q * 8;
    const u16* bpn = Bp + (size_t)n * 12288 + q * 8;
    f32x4 racc;
    #pragma unroll
    for (int i = 0; i < 4; ++i) racc[i] = 0.0f;
    #pragma unroll
    for (int p = 0; p < 2; ++p) {
      const u32 av = p ? 0x0C00u : 0x3C00u;   // 1.0 / 2^-12 amplitude on A side
      #pragma unroll
      for (int j = 0; j < 24; ++j) {
        const int t = wid * 3 + (j >> 3);
        const int wrd = j & 7;
        u32 word = (n < 4) ? zA[(n * 24 + t) * 8 + wrd] : 0u;
        u32 by = (word >> bsh2) & 0xFFu;
        u32 sp = by * 0x8001u;
        u32x4 d;
        d.x = (sp & 0x10001u) * av;
        d.y = ((sp >> 2) & 0x10001u) * av;
        d.z = ((sp >> 4) & 0x10001u) * av;
        d.w = ((sp >> 6) & 0x10001u) * av;
        half8 afr = __builtin_bit_cast(half8, d);
        half8 bfr = *(const half8*)(bpn + p * 6144 + (t * 8 + wrd) * 32);
        racc = __builtin_amdgcn_mfma_f32_16x16x32_f16(afr, bfr, racc, 0, 0, 0);
      }
    }
    // per-wave partials -> LDS (staging/reg overlay is dead after phase 3)
    float* red = (float*)Bs;           // 32 rows x 16 f32 = 2 KB
    if (q == 0) {
      #pragma unroll
      for (int i = 0; i < 4; ++i) red[(wid * 4 + i) * 16 + n] = racc[i];
    }
    __syncthreads();
    if (tid < 64) {
      const int b = tid >> 4, cls = tid & 15;
      float s = 0.0f;
      #pragma unroll
      for (int w = 0; w < 8; ++w) s += red[(w * 4 + b) * 16 + cls];
      if (cls < NCLS) out[(size_t)(b0 + b) * NCLS + cls] = s;
    }
  }
}

// ---------------------------------------------------------------------------
extern "C" void kernel_launch(void* const* d_in, const int* in_sizes, int n_in,
                              void* d_out, int out_size, void* d_ws, size_t ws_size,
                              hipStream_t stream) {
  const float* x  = (const float*)d_in[0];
  const float* W1 = (const float*)d_in[1];
  const float* W2 = (const float*)d_in[2];
  const float* W3 = (const float*)d_in[3];
  const float* Wo = (const float*)d_in[4];
  const float* fs = (const float*)d_in[5];
  const float* es = (const float*)d_in[6];

  char* ws = (char*)d_ws;
  const size_t off_w1 = 0;
  const size_t off_w2 = off_w1 + (size_t)NH * 2 * NF * 2;    // 1.0 MB
  const size_t off_w3 = off_w2 + (size_t)NH * 2 * NH * 2;    // 0.25 MB
  const size_t off_bp = off_w3 + (size_t)NH * 2 * NH * 2;    // 0.25 MB
  const size_t need   = off_bp + (size_t)16 * 12288 * 2;     // 0.375 MB
  if (ws_size < need) return;

  u16* W1hl = (u16*)(ws + off_w1);
  u16* W2hl = (u16*)(ws + off_w2);
  u16* W3hl = (u16*)(ws + off_w3);
  u16* Bp   = (u16*)(ws + off_bp);

  k_prep<<<dim3(1920), dim3(256), 0, stream>>>(W1, W2, W3, Wo, W1hl, W2hl, W3hl, Bp);
  // encoder + three Linear+LIF layers + LI readout in one dispatch
  k_mega<<<dim3(NB / 4), dim3(512), 0, stream>>>(x, fs, es, W1hl, W2hl, W3hl, Bp,
                                                 (float*)d_out);
}

// Round 2
// 232.967 us; speedup vs baseline: 1.3975x; 1.1198x over previous
//
#include <hip/hip_runtime.h>

using u16 = unsigned short;
using u32 = unsigned int;
using u64 = unsigned long long;

typedef _Float16 half8 __attribute__((ext_vector_type(8)));
typedef float  f32x4 __attribute__((ext_vector_type(4)));
typedef u32    u32x4 __attribute__((ext_vector_type(4)));
typedef u32    u32x2 __attribute__((ext_vector_type(2)));

#define T_STEPS 24
#define NB 4096
#define NF 1024
#define NH 256
#define NCLS 10

// split f32 -> hi + 2^-12*lo (lo stored pre-scaled); per-term err ~2^-23|w|
static __device__ __forceinline__ void f16split(float w, u16& hi, u16& lo) {
  _Float16 h = (_Float16)w;
  float hf = (float)h;
  if (__builtin_fabsf(hf) < 6.103515625e-05f) { h = (_Float16)0.0f; hf = 0.0f; }
  float r = __fmul_rn(__fsub_rn(w, hf), 4096.0f);   // exact residual * 2^12
  _Float16 l = (_Float16)r;
  hi = __builtin_bit_cast(u16, h);
  lo = __builtin_bit_cast(u16, l);
}

// ---------------------------------------------------------------------------
// Prep: W1/W2/W3 -> f16 planes INTERLEAVED per 64-k block: row n holds
// [hi(k 0..63) | lo(k 0..63) | hi(k 64..127) | lo(...)...] so consecutive
// 64-k super-chunks in the GEMM are hi/lo of the SAME spike bits.
// ---------------------------------------------------------------------------
__global__ __launch_bounds__(256) void k_prep(const float* __restrict__ W1,
                                              const float* __restrict__ W2,
                                              const float* __restrict__ W3,
                                              u16* __restrict__ W1hl,
                                              u16* __restrict__ W2hl,
                                              u16* __restrict__ W3hl) {
  int blk = blockIdx.x, tid = threadIdx.x;
  const float* src; u16* dst; int K; int g;
  if (blk < 1024)      { src = W1; dst = W1hl; K = 1024; g = blk * 256 + tid; }
  else if (blk < 1280) { src = W2; dst = W2hl; K = 256;  g = (blk - 1024) * 256 + tid; }
  else                 { src = W3; dst = W3hl; K = 256;  g = (blk - 1280) * 256 + tid; }
  int n = g / K, k = g - n * K;
  u16 hi, lo;
  f16split(src[g], hi, lo);
  int p = k >> 6, j = k & 63;
  u16* d = dst + (size_t)n * 2 * K + p * 128 + j;
  d[0] = hi;
  d[64] = lo;
}

// ---------------------------------------------------------------------------
// One Linear+LIF phase. 8 waves as 2m x 4n (wave tile 48m x 64n, acc[3][4]).
// NSC = K'/64 super-chunks; consecutive (even,odd) SCs are hi/lo planes of
// the SAME k-range: even SC loads A bits + expands 6 f16 fragments (av=1.0);
// odd SC derives lo fragments in-register via packed mul by 2^-12 (exact).
// global_load_lds width-16 XOR-swizzled dbuf staging; fused register LIF.
// ---------------------------------------------------------------------------
template <int NSC, int ASTRIDE>
__device__ __forceinline__ void mega_phase(u16* __restrict__ Bs,
                                           const u32* __restrict__ alds,
                                           const u16* __restrict__ wsrc,
                                           u32* __restrict__ zdst,
                                           float scale,
                                           int wid, int lane, int wm, int wn) {
  constexpr int KTOT = NSC * 64;   // u16 per weight row

  const int bsh   = (lane >> 4) * 8;
  const int rbase = (wn * 64 + (lane & 15)) * 64;   // u16 (128 B LDS rows)
  int pu8[2];
  #pragma unroll
  for (int h = 0; h < 2; ++h)
    pu8[h] = (((4 * h + (lane >> 4)) ^ (lane & 7)) * 8);
  const int sunit = ((lane & 7) ^ (lane >> 3)) * 8;  // u16, XOR swizzle
  const u16* gs = wsrc + (size_t)(wid * 32 + (lane >> 3)) * KTOT + sunit;
  const int ldsw = wid * 2048;                       // u16: 32 rows x 64

  auto stage = [&](int s, int b) {
    const u16* g = gs + s * 64;
    #pragma unroll
    for (int r = 0; r < 4; ++r)
      __builtin_amdgcn_global_load_lds(
          (const __attribute__((address_space(1))) u32*)(g + (size_t)r * 8 * KTOT),
          (__attribute__((address_space(3))) u32*)&Bs[b * 16384 + ldsw + r * 512],
          16, 0, 0);
  };

  int arow[3];
  #pragma unroll
  for (int ms = 0; ms < 3; ++ms)
    arow[ms] = (wm * 48 + ms * 16 + (lane & 15)) * ASTRIDE;

  auto expand = [&](u32 word) -> half8 {
    u32 by = (word >> bsh) & 0xFFu;
    u32 sp = by * 0x8001u;
    u32x4 d;
    d.x = (sp & 0x10001u) * 0x3C00u;
    d.y = ((sp >> 2) & 0x10001u) * 0x3C00u;
    d.z = ((sp >> 4) & 0x10001u) * 0x3C00u;
    d.w = ((sp >> 6) & 0x10001u) * 0x3C00u;
    return __builtin_bit_cast(half8, d);
  };

  const _Float16 scl = (_Float16)2.44140625e-4f;   // 2^-12, exact in f16
  const half8 sc8 = {scl, scl, scl, scl, scl, scl, scl, scl};

  f32x4 acc[3][4];
  #pragma unroll
  for (int ms = 0; ms < 3; ++ms)
    #pragma unroll
    for (int ns = 0; ns < 4; ++ns)
      #pragma unroll
      for (int i = 0; i < 4; ++i) acc[ms][ns][i] = 0.0f;

  stage(0, 0);

  half8 afr[3][2];
  #pragma unroll 2
  for (int s = 0; s < NSC; ++s) {
    __syncthreads();   // buf[s&1] staged; all waves done with other buf
    if ((s & 1) == 0) {
      // hi SC: fresh bits (words s, s+1 of the row) -> expand at av=1.0
      u32x2 bw[3];
      #pragma unroll
      for (int ms = 0; ms < 3; ++ms)
        bw[ms] = *(const u32x2*)(alds + arow[ms] + s);
      if (s + 1 < NSC) stage(s + 1, (s + 1) & 1);
      #pragma unroll
      for (int ms = 0; ms < 3; ++ms) {
        afr[ms][0] = expand(bw[ms].x);
        afr[ms][1] = expand(bw[ms].y);
      }
    } else {
      // lo SC: same bits, amplitude 2^-12 -- packed mul, exact
      if (s + 1 < NSC) stage(s + 1, (s + 1) & 1);
      #pragma unroll
      for (int ms = 0; ms < 3; ++ms) {
        afr[ms][0] = afr[ms][0] * sc8;
        afr[ms][1] = afr[ms][1] * sc8;
      }
    }

    const int bufo = (s & 1) * 16384;
    #pragma unroll
    for (int h = 0; h < 2; ++h) {
      #pragma unroll
      for (int ns = 0; ns < 4; ++ns) {
        half8 bfr = *(const half8*)&Bs[bufo + rbase + ns * 1024 + pu8[h]];
        #pragma unroll
        for (int ms = 0; ms < 3; ++ms)
          acc[ms][ns] = __builtin_amdgcn_mfma_f32_16x16x32_f16(afr[ms][h], bfr,
                                                               acc[ms][ns], 0, 0, 0);
      }
    }
  }
  __syncthreads();   // staging dead -> reg overlay safe

  // ---- fused LIF: 2 rounds of 32 cols; C/D: col=lane&15, row=q*4+i ----
  float* reg = (float*)Bs + wid * 1600;   // 48 x 33-pad f32 per wave (51.2 KB)
  const int q   = lane >> 4, c16 = lane & 15;
  const int b2  = lane >> 5, c   = lane & 31;

  #pragma unroll
  for (int r = 0; r < 2; ++r) {
    #pragma unroll
    for (int ms = 0; ms < 3; ++ms)
      #pragma unroll
      for (int j = 0; j < 2; ++j)
        #pragma unroll
        for (int i = 0; i < 4; ++i)
          reg[(ms * 16 + q * 4 + i) * 33 + j * 16 + c16] =
              __fmul_rn(scale, acc[ms][2 * r + j][i]);
    // per-wave region: in-wave lgkm ordering suffices (no barrier)
    float v = 0.0f, ii = 0.0f;
    u32 zw = 0;
    #pragma unroll
    for (int t = 0; t < T_STEPS; ++t) {
      float cv = reg[(b2 * 24 + t) * 33 + c];
      float vdec = __fadd_rn(v, __fmul_rn(0.1f, __fsub_rn(ii, v)));
      float idec = __fmul_rn(0.8f, ii);
      bool z = vdec > 0.33f;
      v = z ? 0.0f : vdec;
      ii = __fadd_rn(idec, cv);
      zw |= ((u32)z) << t;
    }
    #pragma unroll
    for (int t = 0; t < T_STEPS; ++t) {
      u64 m = __ballot((zw >> t) & 1u);
      if (c == 0)
        zdst[((wm * 2 + b2) * 24 + t) * 8 + wn * 2 + r] = (u32)(m >> (b2 * 32));
    }
  }
  __syncthreads();   // zdst complete; reg reads done before next stage(0)
}

// ---------------------------------------------------------------------------
// MEGAKERNEL: one block = 4 batches (96 rows, (b,t) order): encoder + all
// three Linear+LIF layers + factored LI readout. Spike bits never leave LDS.
// ---------------------------------------------------------------------------
__global__ __launch_bounds__(512, 4) void k_mega(const float* __restrict__ x,
                                                 const float* __restrict__ fsp,
                                                 const float* __restrict__ esp,
                                                 const u16* __restrict__ W1hl,
                                                 const u16* __restrict__ W2hl,
                                                 const u16* __restrict__ W3hl,
                                                 const float* __restrict__ Wo,
                                                 float* __restrict__ out) {
  __shared__ __align__(16) u16 Bs[2 * 16384];   // 64 KB staging (+ reg/s overlay)
  __shared__ u32 zE[96 * 34];                   // 13.1 KB enc bits (stride 34; zB overlay)
  __shared__ u32 zA[96 * 8];                    // 3 KB z1 bits (z3 overlay)

  const int tid  = threadIdx.x;
  const int wid  = tid >> 6;
  const int lane = tid & 63;
  const int wm   = wid & 1;
  const int wn   = wid >> 1;          // 0..3
  const int b0   = blockIdx.x * 4;

  // ---- encoder: wave covers (bb = wid>>1, f in [fbase, fbase+512)) ----
  {
    const int bb = wid >> 1;
    const int fbase = (wid & 1) * 512;
    const float c2 = __fmul_rn(2.0f, fsp[0]);
    float cur[8], v[8];
    #pragma unroll
    for (int j = 0; j < 8; ++j) {
      cur[j] = __fmul_rn(c2, x[(size_t)(b0 + bb) * 1024 + fbase + j * 64 + lane]);
      v[j] = 0.0f;
    }
    #pragma unroll
    for (int t = 0; t < T_STEPS; ++t) {
      #pragma unroll
      for (int j = 0; j < 8; ++j) {
        v[j] = __fadd_rn(v[j], __fmul_rn(0.1f, __fsub_rn(cur[j], v[j])));
        bool s = v[j] > 1.0f;
        if (s) v[j] = 0.0f;
        u64 m = __ballot(s);
        if (lane == 0) {
          int w0 = (bb * 24 + t) * 34 + (fbase >> 5) + 2 * j;
          zE[w0] = (u32)m;
          zE[w0 + 1] = (u32)(m >> 32);
        }
      }
    }
  }
  __syncthreads();

  const float s1 = __fmul_rn(1.2f, __fmul_rn(5.0f, esp[0]));
  mega_phase<32, 34>(Bs, zE, W1hl, zA, s1, wid, lane, wm, wn);
  mega_phase<8, 8>(Bs, zA, W2hl, zE, 1.2f, wid, lane, wm, wn);   // zB = zE region
  mega_phase<8, 8>(Bs, zE, W3hl, zA, 1.2f, wid, lane, wm, wn);   // z3 -> zA region

  // ---- factored LI readout ----
  // alpha_t = 0.9^(23-t) - 0.8^(23-t)  (closed form of the LI double
  // recurrence; powers constant-folded at compile time).
  // s[b][h] = sum_t alpha_t * z3[b,t,h]  (4x256 f32 in dead staging LDS),
  // out[b][cls] = sum_h Wo[cls][h] * s[b][h]  (40 wave-level 256-dots).
  {
    float* s_lds = (float*)Bs;   // 4 KB
    #pragma unroll
    for (int r = 0; r < 2; ++r) {
      const int idx = tid + r * 512;          // 0..1023 = b*256 + h
      const int b = idx >> 8, h = idx & 255;
      const u32* zp = zA + (b * 24) * 8 + (h >> 5);
      const int bit = h & 31;
      float p9 = 1.0f, p8 = 1.0f, s = 0.0f;
      #pragma unroll
      for (int e = 0; e < 24; ++e) {          // t = 23-e
        const float a = __fsub_rn(p9, p8);    // 0.9^e - 0.8^e (folded const)
        const u32 word = zp[(23 - e) * 8];    // broadcast across 32 lanes
        s = __fadd_rn(s, ((word >> bit) & 1u) ? a : 0.0f);
        p9 = __fmul_rn(p9, 0.9f);
        p8 = __fmul_rn(p8, 0.8f);
      }
      s_lds[idx] = s;
    }
    __syncthreads();
    // wave wid computes outputs o = wid*5 .. wid*5+4  (40 = 4 b x 10 cls)
    #pragma unroll
    for (int oi = 0; oi < 5; ++oi) {
      const int o = wid * 5 + oi;
      const int b = o / 10, cls = o - (o / 10) * 10;
      f32x4 sv = *(const f32x4*)&s_lds[b * 256 + lane * 4];
      f32x4 wv = *(const f32x4*)&Wo[(size_t)cls * 256 + lane * 4];
      float d = __fadd_rn(__fadd_rn(__fmul_rn(sv.x, wv.x), __fmul_rn(sv.y, wv.y)),
                          __fadd_rn(__fmul_rn(sv.z, wv.z), __fmul_rn(sv.w, wv.w)));
      #pragma unroll
      for (int off2 = 32; off2 >= 1; off2 >>= 1)
        d = __fadd_rn(d, __shfl_down(d, off2));
      if (lane == 0) out[(size_t)(b0 + b) * NCLS + cls] = d;
    }
  }
}

// ---------------------------------------------------------------------------
extern "C" void kernel_launch(void* const* d_in, const int* in_sizes, int n_in,
                              void* d_out, int out_size, void* d_ws, size_t ws_size,
                              hipStream_t stream) {
  const float* x  = (const float*)d_in[0];
  const float* W1 = (const float*)d_in[1];
  const float* W2 = (const float*)d_in[2];
  const float* W3 = (const float*)d_in[3];
  const float* Wo = (const float*)d_in[4];
  const float* fs = (const float*)d_in[5];
  const float* es = (const float*)d_in[6];

  char* ws = (char*)d_ws;
  const size_t off_w1 = 0;
  const size_t off_w2 = off_w1 + (size_t)NH * 2 * NF * 2;    // 1.0 MB
  const size_t off_w3 = off_w2 + (size_t)NH * 2 * NH * 2;    // 0.25 MB
  const size_t need   = off_w3 + (size_t)NH * 2 * NH * 2;    // 0.25 MB
  if (ws_size < need) return;

  u16* W1hl = (u16*)(ws + off_w1);
  u16* W2hl = (u16*)(ws + off_w2);
  u16* W3hl = (u16*)(ws + off_w3);

  k_prep<<<dim3(1536), dim3(256), 0, stream>>>(W1, W2, W3, W1hl, W2hl, W3hl);
  // encoder + three Linear+LIF layers + factored LI readout in one dispatch
  k_mega<<<dim3(NB / 4), dim3(512), 0, stream>>>(x, fs, es, W1hl, W2hl, W3hl, Wo,
                                                 (float*)d_out);
}